// Round 1
// 1177.869 us; speedup vs baseline: 1.4067x; 1.4067x over previous
//
#include <hip/hip_runtime.h>

#define M_TOT 8192
#define N_TOT 11008
#define K_TOT 4096

#define BM 256
#define BN 256
#define BK 64
#define NT (K_TOT / BK)   // 64 K-tiles

typedef _Float16 v8h __attribute__((ext_vector_type(8)));
typedef float v4f __attribute__((ext_vector_type(4)));

// raw barrier (NOT __syncthreads: that inserts s_waitcnt vmcnt(0) and kills the pipeline)
#define BARRIER() asm volatile("s_barrier" ::: "memory")
#define LGKM0()   asm volatile("s_waitcnt lgkmcnt(0)" ::: "memory")
#define VMCNT(n)  asm volatile("s_waitcnt vmcnt(" #n ")" ::: "memory")

// ---------------------------------------------------------------------------
// Convert input fp32 -> fp16 (each thread: 8 elements)
// ---------------------------------------------------------------------------
__global__ void cvt_a_kernel(const float* __restrict__ in, _Float16* __restrict__ out) {
    int idx = blockIdx.x * blockDim.x + threadIdx.x;
    float4 f0 = ((const float4*)in)[idx * 2];
    float4 f1 = ((const float4*)in)[idx * 2 + 1];
    v8h h;
    h[0] = (_Float16)f0.x; h[1] = (_Float16)f0.y;
    h[2] = (_Float16)f0.z; h[3] = (_Float16)f0.w;
    h[4] = (_Float16)f1.x; h[5] = (_Float16)f1.y;
    h[6] = (_Float16)f1.z; h[7] = (_Float16)f1.w;
    ((v8h*)out)[idx] = h;
}

// ---------------------------------------------------------------------------
// Convert qweight int32 (int8-valued, exact in fp16) -> fp16
// ---------------------------------------------------------------------------
__global__ void cvt_w_kernel(const int* __restrict__ q, _Float16* __restrict__ out) {
    int idx = blockIdx.x * blockDim.x + threadIdx.x;
    int4 q0 = ((const int4*)q)[idx * 2];
    int4 q1 = ((const int4*)q)[idx * 2 + 1];
    v8h h;
    h[0] = (_Float16)q0.x; h[1] = (_Float16)q0.y;
    h[2] = (_Float16)q0.z; h[3] = (_Float16)q0.w;
    h[4] = (_Float16)q1.x; h[5] = (_Float16)q1.y;
    h[6] = (_Float16)q1.z; h[7] = (_Float16)q1.w;
    ((v8h*)out)[idx] = h;
}

// ---------------------------------------------------------------------------
// 16B async global->LDS copy (dest = wave-uniform base + lane*16)
// ---------------------------------------------------------------------------
__device__ __forceinline__ void load_lds16(const void* g, void* l) {
    __builtin_amdgcn_global_load_lds(
        (const __attribute__((address_space(1))) unsigned int*)g,
        (__attribute__((address_space(3))) unsigned int*)l,
        16, 0, 0);
}

// Stage one 256-row x 64-col f16 panel (A or B) of tile kt: 4 rounds of 64 rows.
// g already includes per-thread (srow, swizzled chunk) offsets; d already
// includes wave*1024. LDS dest is LINEAR (rule #21): the swizzle lives in the
// per-lane GLOBAL source address, its inverse in the ds_read offsets.
__device__ __forceinline__ void stage4(const _Float16* g, char* d) {
    load_lds16(g,                 d);
    load_lds16(g +  64L * K_TOT,  d + 8192);
    load_lds16(g + 128L * K_TOT,  d + 16384);
    load_lds16(g + 192L * K_TOT,  d + 24576);
}

__device__ __forceinline__ v4f mfma_(v8h a, v8h b, v4f c) {
    return __builtin_amdgcn_mfma_f32_16x16x32_f16(a, b, c, 0, 0, 0);
}

// ---------------------------------------------------------------------------
// One K-tile = 4 phases. Per wave: 128x64 output = 8mi x 4ni fragments.
//  P1: read af(mi0..3)+bfA(ni0,1)          -> MFMA M0xN0 (16)
//  P2: read bfB(ni2,3)                     -> MFMA M0xN1 (16)
//  P3: read af(mi4..7); stage B(t+2)       -> MFMA M1xN1 (16)
//  P4: stage A(t+2)                        -> MFMA M1xN0 (16); vmcnt(8); bar
// vmcnt(8) ledger: the newest 8 in-flight loads are always tile t+2's
// (B@P3 + A@P4), so all of tile t+1's staging is complete at its boundary.
// Only FINAL drains to 0 (last tile's data must land).
// ---------------------------------------------------------------------------
template<int BUF, bool DO_STAGE, bool FINAL>
__device__ __forceinline__ void tile_step(
    const char* lds, const _Float16* a_src, const _Float16* b_src,
    char* a_dst, char* b_dst,
    int a_row0, int b_row0, int swz0, int swz1, int kt2,
    v4f (&acc)[8][4])
{
    const char* Ab = lds + BUF * 32768;
    const char* Bb = lds + 65536 + BUF * 32768;
    v8h af[4][2], bfA[2][2], bfB[2][2];

    // ---- P1: M0 x N0 ----
#pragma unroll
    for (int mi = 0; mi < 4; ++mi) {
        af[mi][0] = *(const v8h*)(Ab + a_row0 + mi * 2048 + swz0);
        af[mi][1] = *(const v8h*)(Ab + a_row0 + mi * 2048 + swz1);
    }
#pragma unroll
    for (int ni = 0; ni < 2; ++ni) {
        bfA[ni][0] = *(const v8h*)(Bb + b_row0 + ni * 2048 + swz0);
        bfA[ni][1] = *(const v8h*)(Bb + b_row0 + ni * 2048 + swz1);
    }
    BARRIER(); LGKM0();
    __builtin_amdgcn_s_setprio(1);
#pragma unroll
    for (int mi = 0; mi < 4; ++mi)
#pragma unroll
        for (int ni = 0; ni < 2; ++ni) {
            acc[mi][ni] = mfma_(af[mi][0], bfA[ni][0], acc[mi][ni]);
            acc[mi][ni] = mfma_(af[mi][1], bfA[ni][1], acc[mi][ni]);
        }
    __builtin_amdgcn_s_setprio(0);
    BARRIER();

    // ---- P2: M0 x N1 ----
#pragma unroll
    for (int ni = 0; ni < 2; ++ni) {
        bfB[ni][0] = *(const v8h*)(Bb + b_row0 + (2 + ni) * 2048 + swz0);
        bfB[ni][1] = *(const v8h*)(Bb + b_row0 + (2 + ni) * 2048 + swz1);
    }
    BARRIER(); LGKM0();
    __builtin_amdgcn_s_setprio(1);
#pragma unroll
    for (int mi = 0; mi < 4; ++mi)
#pragma unroll
        for (int ni = 0; ni < 2; ++ni) {
            acc[mi][2 + ni] = mfma_(af[mi][0], bfB[ni][0], acc[mi][2 + ni]);
            acc[mi][2 + ni] = mfma_(af[mi][1], bfB[ni][1], acc[mi][2 + ni]);
        }
    __builtin_amdgcn_s_setprio(0);
    BARRIER();

    // ---- P3: M1 x N1 (+ stage B of tile kt2; B regions free after P2 bar) ----
#pragma unroll
    for (int mi = 0; mi < 4; ++mi) {
        af[mi][0] = *(const v8h*)(Ab + a_row0 + (4 + mi) * 2048 + swz0);
        af[mi][1] = *(const v8h*)(Ab + a_row0 + (4 + mi) * 2048 + swz1);
    }
    if (DO_STAGE) stage4(b_src + (long)kt2 * BK, b_dst + BUF * 32768);
    BARRIER(); LGKM0();
    __builtin_amdgcn_s_setprio(1);
#pragma unroll
    for (int mi = 0; mi < 4; ++mi)
#pragma unroll
        for (int ni = 0; ni < 2; ++ni) {
            acc[4 + mi][2 + ni] = mfma_(af[mi][0], bfB[ni][0], acc[4 + mi][2 + ni]);
            acc[4 + mi][2 + ni] = mfma_(af[mi][1], bfB[ni][1], acc[4 + mi][2 + ni]);
        }
    __builtin_amdgcn_s_setprio(0);
    BARRIER();

    // ---- P4: M1 x N0 (+ stage A of tile kt2; A regions free after P3 bar) ----
    if (DO_STAGE) stage4(a_src + (long)kt2 * BK, a_dst + BUF * 32768);
    BARRIER();
    __builtin_amdgcn_s_setprio(1);
#pragma unroll
    for (int mi = 0; mi < 4; ++mi)
#pragma unroll
        for (int ni = 0; ni < 2; ++ni) {
            acc[4 + mi][ni] = mfma_(af[mi][0], bfA[ni][0], acc[4 + mi][ni]);
            acc[4 + mi][ni] = mfma_(af[mi][1], bfA[ni][1], acc[4 + mi][ni]);
        }
    __builtin_amdgcn_s_setprio(0);
    if (FINAL) { VMCNT(0); } else { VMCNT(8); }
    BARRIER();   // doubles as next tile's "staging landed" barrier
}

// ---------------------------------------------------------------------------
// GEMM: C[m,n] = scale[n] * sum_k A16[m,k]*W16[n,k] + bias[n]
// 256x256 tile, BK=64, 512 threads (8 waves, 2Mx4N), 128 KiB LDS double-buffer,
// 8-phase schedule with counted vmcnt (never 0 in main loop) + setprio + both-
// sides XOR swizzle (LDS slot s of row r holds k-chunk s^(r&7)).
// ---------------------------------------------------------------------------
__global__ __launch_bounds__(512, 2) void qgemm_kernel(
    const _Float16* __restrict__ A,
    const _Float16* __restrict__ Bw,
    const float* __restrict__ w_scale,
    const float* __restrict__ bias_g,
    float* __restrict__ C)
{
    __shared__ __align__(16) char lds[131072];
    // A buf b: [b*32768, +32768) ; B buf b: [65536 + b*32768, +32768)
    // panel row r (0..255) at r*128 bytes; 8 slots of 16B; slot s = chunk s^(r&7)

    const int tid  = threadIdx.x;
    const int lane = tid & 63;
    const int wave = tid >> 6;      // 0..7
    const int wm   = wave >> 2;     // 0..1  (M half: rows wm*128..)
    const int wn   = wave & 3;      // 0..3  (N quarter: cols wn*64..)
    const int fr   = lane & 15;
    const int quad = lane >> 4;

    const long brow = (long)blockIdx.y * BM;
    const long bcol = (long)blockIdx.x * BN;

    // staging: thread covers row srow (of each 64-row round), 16B chunk schunk.
    // schunk is the inverse-swizzled global source (rule #21).
    const int srow   = tid >> 3;                    // 0..63
    const int schunk = (tid & 7) ^ (srow & 7);
    const _Float16* a_src = A  + (brow + srow) * (long)K_TOT + schunk * 8;
    const _Float16* b_src = Bw + (bcol + srow) * (long)K_TOT + schunk * 8;
    char* a_dst = (char*)lds + wave * 1024;
    char* b_dst = (char*)lds + 65536 + wave * 1024;

    // fragment read addressing (swizzled): chunk c=ks*4+quad at slot c^(fr&7)
    const int swz0 = ((0 + quad) ^ (fr & 7)) * 16;  // ks=0
    const int swz1 = ((4 + quad) ^ (fr & 7)) * 16;  // ks=1
    const int a_row0 = (wm * 128 + fr) * 128;       // byte offset of row
    const int b_row0 = (wn * 64 + fr) * 128;

    v4f acc[8][4];
#pragma unroll
    for (int i = 0; i < 8; ++i)
#pragma unroll
        for (int j = 0; j < 4; ++j)
            acc[i][j] = (v4f)0.0f;

    // prologue: stage tiles 0 (buf0) and 1 (buf1); order B,A,B,A so the newest
    // 8 in-flight loads at the first wait are tile 1's.
    stage4(b_src,      b_dst);
    stage4(a_src,      a_dst);
    stage4(b_src + BK, b_dst + 32768);
    stage4(a_src + BK, a_dst + 32768);
    VMCNT(8);     // tile 0 landed; tile 1 still in flight
    BARRIER();

    for (int t = 0; t < NT - 2; t += 2) {
        tile_step<0, true, false>(lds, a_src, b_src, a_dst, b_dst,
                                  a_row0, b_row0, swz0, swz1, t + 2, acc);
        tile_step<1, true, false>(lds, a_src, b_src, a_dst, b_dst,
                                  a_row0, b_row0, swz0, swz1, t + 3, acc);
    }
    // epilogue tiles: no staging; first one must fully drain (vmcnt 0) so the
    // last tile's data is guaranteed in LDS.
    tile_step<0, false, true>(lds, a_src, b_src, a_dst, b_dst,
                              a_row0, b_row0, swz0, swz1, 0, acc);
    tile_step<1, false, true>(lds, a_src, b_src, a_dst, b_dst,
                              a_row0, b_row0, swz0, swz1, 0, acc);

    // Epilogue: C/D layout col = lane&15, row = quad*4 + reg
#pragma unroll
    for (int ni = 0; ni < 4; ++ni) {
        const int n = (int)bcol + wn * 64 + ni * 16 + fr;
        const float sc = w_scale[n];
        const float bi = bias_g[n];
#pragma unroll
        for (int mi = 0; mi < 8; ++mi) {
            const long row0 = brow + wm * 128 + mi * 16 + quad * 4;
            float* cp = C + row0 * N_TOT + n;
#pragma unroll
            for (int r = 0; r < 4; ++r)
                cp[(long)r * N_TOT] = acc[mi][ni][r] * sc + bi;
        }
    }
}

// ---------------------------------------------------------------------------
// Fallback (only if ws_size too small): correct but slow
// ---------------------------------------------------------------------------
__global__ void naive_kernel(const float* __restrict__ in, const int* __restrict__ q,
                             const float* __restrict__ sc, const float* __restrict__ bi,
                             float* __restrict__ out) {
    long idx = (long)blockIdx.x * 256 + threadIdx.x;
    int m = (int)(idx / N_TOT), n = (int)(idx % N_TOT);
    const float* a = in + (long)m * K_TOT;
    const int* w = q + (long)n * K_TOT;
    float s = 0.f;
    for (int k = 0; k < K_TOT; k += 4) {
        s += a[k] * (float)w[k] + a[k + 1] * (float)w[k + 1] +
             a[k + 2] * (float)w[k + 2] + a[k + 3] * (float)w[k + 3];
    }
    out[idx] = s * sc[n] + bi[n];
}

extern "C" void kernel_launch(void* const* d_in, const int* in_sizes, int n_in,
                              void* d_out, int out_size, void* d_ws, size_t ws_size,
                              hipStream_t stream) {
    const float* input   = (const float*)d_in[0];
    const int*   qweight = (const int*)d_in[1];
    const float* w_scale = (const float*)d_in[2];
    // d_in[3] = w_zp (all zeros, symmetric quant -> no-op)
    const float* bias    = (const float*)d_in[4];
    float* out = (float*)d_out;

    const size_t needA = (size_t)M_TOT * K_TOT * sizeof(_Float16);  // 64 MiB
    const size_t needW = (size_t)N_TOT * K_TOT * sizeof(_Float16);  // 86 MiB

    if (ws_size >= needA + needW) {
        _Float16* A16 = (_Float16*)d_ws;
        _Float16* W16 = (_Float16*)((char*)d_ws + needA);

        cvt_a_kernel<<<(M_TOT * (long)K_TOT / 8) / 256, 256, 0, stream>>>(input, A16);
        cvt_w_kernel<<<(N_TOT * (long)K_TOT / 8) / 256, 256, 0, stream>>>(qweight, W16);

        dim3 grid(N_TOT / BN, M_TOT / BM);   // 43 x 32
        qgemm_kernel<<<grid, 512, 0, stream>>>(A16, W16, w_scale, bias, out);
    } else {
        naive_kernel<<<(long)M_TOT * N_TOT / 256, 256, 0, stream>>>(
            input, qweight, w_scale, bias, out);
    }
}